// Round 13
// baseline (268.031 us; speedup 1.0000x reference)
//
#include <hip/hip_runtime.h>
#include <hip/hip_bf16.h>
#include <stdint.h>

#define D_    1024
#define L_    2048
#define B_    4
#define NHEAD 8
#define HDIM  128
#define BL_   (B_*L_)   // 8192
#define EPS_  1e-6f

typedef __attribute__((ext_vector_type(8))) short short8;
typedef __attribute__((ext_vector_type(4))) float f32x4;

__device__ __forceinline__ unsigned short f2bf(float f) {
  unsigned u = __builtin_bit_cast(unsigned, f);
  unsigned r = 0x7fffu + ((u >> 16) & 1u);
  return (unsigned short)((u + r) >> 16);
}
__device__ __forceinline__ float bf2f(unsigned short h) {
  return __builtin_bit_cast(float, ((unsigned)h) << 16);
}
// fast silu: raw v_rcp (~1 ulp) instead of correctly-rounded f32 divide;
// output goes to bf16 so the error is invisible.
__device__ __forceinline__ float silu_f(float x) {
  return x * __builtin_amdgcn_rcpf(1.f + __expf(-x));
}
// pack two f32 -> two bf16 (RNE) in one instruction
__device__ __forceinline__ unsigned cvt_pk_bf16(float lo, float hi) {
  unsigned r;
  asm("v_cvt_pk_bf16_f32 %0, %1, %2" : "=v"(r) : "v"(lo), "v"(hi));
  return r;
}

// async global->LDS, 16B per lane; LDS dest is wave-uniform base + lane*16
__device__ __forceinline__ void gll16(const void* g, void* l) {
  auto gp = reinterpret_cast<const __attribute__((address_space(1))) unsigned*>(
      reinterpret_cast<uintptr_t>(g));
  auto lp = reinterpret_cast<__attribute__((address_space(3))) unsigned*>(
      (unsigned)reinterpret_cast<uintptr_t>(l));
  __builtin_amdgcn_global_load_lds(gp, lp, 16, 0, 0);
}

// ---------------- weight transpose + cast: w[1024][1024] f32 -> wt[1024][1024] bf16 (wt = w^T)
__global__ __launch_bounds__(256) void wt_kernel(
    const float* __restrict__ wu, const float* __restrict__ wq,
    const float* __restrict__ wk, const float* __restrict__ wv,
    const float* __restrict__ wo, unsigned short* __restrict__ wt)
{
  __shared__ float t[64][65];
  int mat = blockIdx.z;
  const float* src = mat==0?wu: mat==1?wq: mat==2?wk: mat==3?wv: wo;
  unsigned short* dst = wt + (size_t)mat*D_*D_;
  int r0 = blockIdx.y*64, c0 = blockIdx.x*64;
  int tid = threadIdx.x;
  for (int i = 0; i < 16; ++i) {
    int e = i*256 + tid; int r = e>>6, c = e&63;
    t[r][c] = src[(size_t)(r0+r)*D_ + c0 + c];
  }
  __syncthreads();
  for (int i = 0; i < 16; ++i) {
    int e = i*256 + tid; int r = e>>6, c = e&63;
    dst[(size_t)(c0+r)*D_ + r0 + c] = f2bf(t[c][r]);
  }
}

// ---------------- input LN -> bf16 x
__global__ __launch_bounds__(256) void ln_in_kernel(
    const float* __restrict__ in, const float* __restrict__ gamma,
    const float* __restrict__ beta, unsigned short* __restrict__ x)
{
  int row = blockIdx.x, tid = threadIdx.x;
  float4 v = ((const float4*)(in + (size_t)row*D_))[tid];
  float s = v.x+v.y+v.z+v.w;
  float ss = v.x*v.x + v.y*v.y + v.z*v.z + v.w*v.w;
  #pragma unroll
  for (int o = 32; o; o >>= 1) { s += __shfl_down(s,o); ss += __shfl_down(ss,o); }
  __shared__ float red[8];
  int lane = tid&63, wid = tid>>6;
  if (lane==0) { red[wid]=s; red[4+wid]=ss; }
  __syncthreads();
  s = red[0]+red[1]+red[2]+red[3];
  ss = red[4]+red[5]+red[6]+red[7];
  float mean = s * (1.f/D_);
  float var  = ss * (1.f/D_) - mean*mean;
  float rstd = rsqrtf(var + EPS_);
  float4 g = ((const float4*)gamma)[tid], b = ((const float4*)beta)[tid];
  ushort4 o;
  o.x = f2bf((v.x-mean)*rstd*g.x + b.x);
  o.y = f2bf((v.y-mean)*rstd*g.y + b.y);
  o.z = f2bf((v.z-mean)*rstd*g.z + b.z);
  o.w = f2bf((v.w-mean)*rstd*g.w + b.w);
  ((ushort4*)(x + (size_t)row*D_))[tid] = o;
}

// ---------------- 256x(BN) phased GEMM, C = A[M][1024] * Bt[cols][1024]^T
// 8 waves, BK=32 per phase, 4-slice LDS ring (2 K-tiles), counted vmcnt (T4).
// R13: UNFENCED phase interior. No setprio (T5 is null/negative on this
// structure per m190 regime gate), no intra-phase sched_barriers -> the
// compiler's fine-grained lgkmcnt interleaves the 12 ds_reads with the 32
// MFMAs (m97-documented behavior), overlapping the per-CU LDS burst (~1150cy)
// with the per-SIMD MFMA stream (~1240cy) instead of running them serially.
// Phase = {ds_reads; stage(g+3); 32 MFMA (compiler-scheduled); lgkmcnt(0)
// [next phase's gll16 overwrites the slice just read]; vmcnt(counted); bar}.
// Ring safety: reads at g of slice staged at g-3 covered by vmcnt at bar(g-1);
// stage(g)->slice (g+3)&3 never collides with reads of slice g&3.
// MODE 0: BN=256, silu epilogue -> u/q/k bf16 + v transposed; MODE 1: BN=128, acc+resid f32.
template<int MODE>
__global__ __launch_bounds__(512) __attribute__((amdgpu_waves_per_eu(2,2))) void gemm8p(
    const unsigned short* __restrict__ A, const unsigned short* __restrict__ Bt,
    unsigned short* __restrict__ o_u, unsigned short* __restrict__ o_q,
    unsigned short* __restrict__ o_k, unsigned short* __restrict__ o_vt,
    const float* __restrict__ resid, float* __restrict__ o_f)
{
  constexpr int BN  = (MODE==0) ? 256 : 128;
  constexpr int WN  = (MODE==0) ? 4 : 2;       // waves along N
  constexpr int WTM = (MODE==0) ? 128 : 64;    // wave tile rows (256/WM)
  constexpr int MF  = WTM/16;                  // m-frags per wave: 8 or 4
  constexpr int BNS = BN*32;                   // B slice ushorts (BK=32)
  constexpr int BOFF = 32768;                  // A region: 4 slices * 8192
  constexpr int RG  = BN/64;                   // row-groups per kk8 in B slice
  constexpr int NBCHW = (BNS/512)/8;           // B chunks per wave
  const int K = 1024;

  __shared__ unsigned short lds[BOFF + 4*BNS];

  int lane = threadIdx.x & 63, wid = threadIdx.x >> 6;
  int wr = wid / WN, wc = wid % WN;
  int m0 = blockIdx.x * 256;
  int n0 = blockIdx.y * BN;
  const unsigned short* Ab = A + (size_t)m0*K;
  const unsigned short* Bb = Bt + (size_t)n0*K;

  f32x4 acc[MF][4] = {};

  auto stage = [&](int dbs, int k0) {
    #pragma unroll
    for (int j = 0; j < 2; ++j) {
      int c = wid*2 + j;                 // 16 A chunks
      int row = (c&3)*64 + lane;
      int kof = k0 + ((c>>2)<<3);
      gll16(Ab + (size_t)row*K + kof, &lds[dbs*8192 + c*512]);
    }
    #pragma unroll
    for (int j = 0; j < NBCHW; ++j) {
      int c = wid*NBCHW + j;             // BNS/512 B chunks
      int kk8 = c / RG, rg = c % RG;
      int row = rg*64 + lane;
      int kof = k0 + (kk8<<3);
      gll16(Bb + (size_t)row*K + kof, &lds[BOFF + dbs*BNS + c*512]);
    }
  };

  // prologue: stage phases 0..3 (K-tiles 0,1), wait for phase 0's slice
  #pragma unroll
  for (int gp = 0; gp < 4; ++gp) stage(gp, gp*32);
  if constexpr (MODE==0) asm volatile("s_waitcnt vmcnt(12)" ::: "memory");
  else                   asm volatile("s_waitcnt vmcnt(9)"  ::: "memory");
  __builtin_amdgcn_s_barrier();

  auto do_phase = [&](int g, bool dostage) {
    const int bs = g & 3;
    const int kk4 = lane>>4, l15 = lane&15;
    short8 af[MF], bfr[4];
    const int ab = bs*8192 + kk4*2048 + (wr*WTM + l15)*8;
    const int bb = BOFF + bs*BNS + kk4*(BN*8) + (wc*64 + l15)*8;
    // reads first; no fences after -> compiler interleaves MFMA via fine lgkmcnt
    #pragma unroll
    for (int n = 0; n < 4; ++n) bfr[n] = *(const short8*)&lds[bb + n*128];
    #pragma unroll
    for (int m = 0; m < MF; ++m) af[m] = *(const short8*)&lds[ab + m*128];
    if (dostage) {
      int tp = g + 3;
      int k0 = (tp < 32 ? tp : 31) * 32;   // clamp SOURCE only; dest region stays tp&3
      stage(tp & 3, k0);
    }
    #pragma unroll
    for (int m = 0; m < MF; ++m)
      #pragma unroll
      for (int n = 0; n < 4; ++n)
        acc[m][n] = __builtin_amdgcn_mfma_f32_16x16x32_bf16(af[m], bfr[n], acc[m][n], 0,0,0);
    asm volatile("s_waitcnt lgkmcnt(0)" ::: "memory");
    if constexpr (MODE==0) asm volatile("s_waitcnt vmcnt(8)" ::: "memory");
    else                   asm volatile("s_waitcnt vmcnt(6)" ::: "memory");
    __builtin_amdgcn_s_barrier();
  };

  do_phase(0, false);
  #pragma unroll
  for (int g = 1; g < 32; ++g) do_phase(g, true);

  if constexpr (MODE == 0) {
    int mat = n0 >> 10;
    int jb = n0 & 1023;
    #pragma unroll
    for (int m = 0; m < MF; ++m) {
      int t_ = m0 + wr*WTM + m*16 + ((lane>>4)<<2);
      #pragma unroll
      for (int n = 0; n < 4; ++n) {
        int jj = jb + wc*64 + n*16 + (lane&15);
        float p0 = silu_f(acc[m][n][0]);
        float p1 = silu_f(acc[m][n][1]);
        float p2 = silu_f(acc[m][n][2]);
        float p3 = silu_f(acc[m][n][3]);
        if (mat == 3) {
          int b = t_ >> 11, tt = t_ & 2047;
          int nn = jj >> 7, h = jj & 127;
          ushort4 pk;
          pk.x = f2bf(p0); pk.y = f2bf(p1); pk.z = f2bf(p2); pk.w = f2bf(p3);
          *(ushort4*)&o_vt[(((size_t)(b*NHEAD+nn))*HDIM + h)*L_ + tt] = pk;
        } else {
          unsigned short* dst = mat==0 ? o_u : (mat==1 ? o_q : o_k);
          dst[(size_t)(t_+0)*D_ + jj] = f2bf(p0);
          dst[(size_t)(t_+1)*D_ + jj] = f2bf(p1);
          dst[(size_t)(t_+2)*D_ + jj] = f2bf(p2);
          dst[(size_t)(t_+3)*D_ + jj] = f2bf(p3);
        }
      }
    }
  } else {
    #pragma unroll
    for (int m = 0; m < MF; ++m) {
      int t_ = m0 + wr*WTM + m*16 + ((lane>>4)<<2);
      #pragma unroll
      for (int n = 0; n < 4; ++n) {
        int jj = n0 + wc*64 + n*16 + (lane&15);
        #pragma unroll
        for (int r = 0; r < 4; ++r)
          o_f[(size_t)(t_+r)*D_ + jj] = acc[m][n][r] + resid[(size_t)(t_+r)*D_ + jj];
      }
    }
  }
}

// ---------------- causal pointwise-silu attention, same-tile cooperative pairing
// (unchanged from R11: attn ~79us — see R11 notes)
__global__ __launch_bounds__(512) __attribute__((amdgpu_waves_per_eu(2,2))) void attn_kernel(
    const unsigned short* __restrict__ gq, const unsigned short* __restrict__ gk,
    const unsigned short* __restrict__ gvt, unsigned short* __restrict__ attn_out)
{
  __shared__ unsigned short SM[49152];   // 96 KB
  int id = blockIdx.x;
  int x = id & 7, c2 = (id >> 3) & 3, q = id >> 5;   // XCD, head-group, pair idx
  int bh = 8*c2 + x;
  int b = bh >> 3, n = bh & 7;
  const unsigned short* qb = gq + (size_t)b*L_*D_ + n*HDIM;
  const unsigned short* kb = gk + (size_t)b*L_*D_ + n*HDIM;
  const unsigned short* vb = gvt + (size_t)bh*HDIM*L_;
  unsigned short* ob = attn_out + (size_t)b*L_*D_ + n*HDIM;
  int lane = threadIdx.x & 63, wid = threadIdx.x >> 6;
  int wsel = wid >> 2, wq = wid & 3;      // set, wave-in-set
  int wr = wq >> 1, wc = wq & 1;
  int hi = lane >> 4, l15 = lane & 15;
  unsigned short* Kbuf = SM + (wsel ? 8192 : 0);
  unsigned short* Vbuf = SM + 16384 + (wsel ? 8192 : 0);
  unsigned short* Pbuf = SM + 32768 + (wsel ? 8192 : 0);
  unsigned short* Qbuf = SM + 32768;      // 32KB staging (PA+PB region)
  float* Cbuf = (float*)SM;               // 64KB combine (KA..VB region)

  for (int uu = 0; uu < 2; ++uu) {
    int ti = uu ? q : (15 - q);
    int t0 = ti * 128;
    // ---- stage Q tile [h/8(16)][t(128)][8] (all 8 waves, 32 chunks)
    #pragma unroll
    for (int i = 0; i < 4; ++i) {
      int cc = wid*4 + i;
      gll16(qb + (size_t)(t0 + ((cc&1)<<6) + lane)*D_ + ((cc>>1)<<3), &Qbuf[cc*512]);
    }
    __syncthreads();
    short8 qf[4][4];
    #pragma unroll
    for (int kk = 0; kk < 4; ++kk) {
      int kbase = (kk*4 + hi)*1024;
      #pragma unroll
      for (int fn = 0; fn < 4; ++fn)
        qf[kk][fn] = *(const short8*)&Qbuf[kbase + (wc*64 + fn*16 + l15)*8];
    }
    __syncthreads();   // qf in regs -> PA/PB free
    // ---- stage K/V chunk (wsel) for own set: K[h/8(16)][64][8], V[s/8(8)][128][8]
    #pragma unroll
    for (int i = 0; i < 4; ++i) {
      int cc = wq*4 + i;
      gll16(kb + (size_t)(wsel*64 + lane)*D_ + (cc<<3), &Kbuf[cc*512]);
      gll16(vb + (size_t)(((cc&1)<<6) + lane)*L_ + wsel*64 + ((cc>>1)<<3), &Vbuf[cc*512]);
    }
    __syncthreads();   // vmcnt(0): K0/V0 ready

    f32x4 oacc[4][4] = {};
    for (int j = 0; j <= ti; ++j) {
      bool stg = (j < ti);
      int cnext = 2*(j+1) + wsel;          // next 64-s chunk for this set
      // ===== R1: QK || K_next->regs || P-phase =====
      f32x4 sacc[2][4] = {};
      __builtin_amdgcn_s_setprio(1);
      #pragma unroll
      for (int kk = 0; kk < 4; ++kk) {
        int kbase = (kk*4 + hi)*512;
        short8 kf[2];
        #pragma unroll
        for (int fm = 0; fm < 2; ++fm)
          kf[fm] = *(const short8*)&Kbuf[kbase + (wr*32 + fm*16 + l15)*8];
        #pragma unroll
        for (int fm = 0; fm < 2; ++fm)
          #pragma unroll
          for (int fn = 0; fn < 4; ++fn)
            sacc[fm][fn] = __builtin_amdgcn_mfma_f32_16x16x32_bf16(kf[fm], qf[kk][fn], sacc[fm][fn], 0,0,0);
      }
      __builtin_amdgcn_s_setprio(0);
      uint4 kreg[4];
      if (stg) {
        #pragma unroll
        for (int i = 0; i < 4; ++i) {
          int cc = wq*4 + i;
          kreg[i] = *(const uint4*)(kb + (size_t)(cnext*64 + lane)*D_ + (cc<<3));
        }
      }
      // P = silu(S)/L with causal mask -> own P buffer [s/8(8)][t(128)][8]
      {
        bool diag = (j == ti);
        int maskoff = wsel*64;
        #pragma unroll
        for (int fm = 0; fm < 2; ++fm) {
          int sb = wr*32 + fm*16 + (hi<<2);
          #pragma unroll
          for (int fn = 0; fn < 4; ++fn) {
            int tl = wc*64 + fn*16 + l15;
            float pv[4];
            #pragma unroll
            for (int r = 0; r < 4; ++r) {
              float sv = silu_f(sacc[fm][fn][r]) * (1.f/2048.f);
              if (diag && (tl < maskoff + sb + r)) sv = 0.f;
              pv[r] = sv;
            }
            int a0 = (sb>>3)*1024 + tl*8 + (sb&7);
            *(unsigned*)&Pbuf[a0]   = cvt_pk_bf16(pv[0], pv[1]);
            *(unsigned*)&Pbuf[a0+2] = cvt_pk_bf16(pv[2], pv[3]);
          }
        }
      }
      // barrier A: P visible; K-regs + V(st) landed; QK ds_reads drained
      asm volatile("s_waitcnt vmcnt(0) lgkmcnt(0)" ::: "memory");
      __builtin_amdgcn_sched_barrier(0);
      __builtin_amdgcn_s_barrier();
      __builtin_amdgcn_sched_barrier(0);
      // ===== R2: K-commit || PV =====
      if (stg) {
        #pragma unroll
        for (int i = 0; i < 4; ++i) {
          int cc = wq*4 + i;
          *(uint4*)&Kbuf[cc*512 + lane*8] = kreg[i];
        }
      }
      __builtin_amdgcn_s_setprio(1);
      #pragma unroll
      for (int kk = 0; kk < 2; ++kk) {
        int kbase = (kk*4 + hi)*1024;
        short8 pa[4], vf[4];
        #pragma unroll
        for (int fm = 0; fm < 4; ++fm)
          pa[fm] = *(const short8*)&Pbuf[kbase + (wr*64 + fm*16 + l15)*8];
        #pragma unroll
        for (int fn = 0; fn < 4; ++fn)
          vf[fn] = *(const short8*)&Vbuf[kbase + (wc*64 + fn*16 + l15)*8];
        #pragma unroll
        for (int fm = 0; fm < 4; ++fm)
          #pragma unroll
          for (int fn = 0; fn < 4; ++fn)
            oacc[fm][fn] = __builtin_amdgcn_mfma_f32_16x16x32_bf16(pa[fm], vf[fn], oacc[fm][fn], 0,0,0);
      }
      __builtin_amdgcn_s_setprio(0);
      // barrier B: PV reads + K-commit writes drained
      asm volatile("s_waitcnt lgkmcnt(0)" ::: "memory");
      __builtin_amdgcn_sched_barrier(0);
      __builtin_amdgcn_s_barrier();
      __builtin_amdgcn_sched_barrier(0);
      // tail: issue V_next (lands under next R1; drained at next barrier A)
      if (stg) {
        #pragma unroll
        for (int i = 0; i < 4; ++i) {
          int cc = wq*4 + i;
          gll16(vb + (size_t)(((cc&1)<<6) + lane)*L_ + cnext*64 + ((cc>>1)<<3), &Vbuf[cc*512]);
        }
        __builtin_amdgcn_sched_barrier(0);
      }
    }
    // ---- combine partial O: set B writes f32 -> Cbuf, set A adds & stores
    if (wsel == 1) {
      #pragma unroll
      for (int fm = 0; fm < 4; ++fm) {
        int tl = wr*64 + fm*16 + (hi<<2);
        #pragma unroll
        for (int fn = 0; fn < 4; ++fn) {
          int h = wc*64 + fn*16 + l15;
          #pragma unroll
          for (int r = 0; r < 4; ++r)
            Cbuf[(tl+r)*128 + h] = oacc[fm][fn][r];
        }
      }
    }
    asm volatile("s_waitcnt lgkmcnt(0)" ::: "memory");
    __builtin_amdgcn_s_barrier();
    __builtin_amdgcn_sched_barrier(0);
    if (wsel == 0) {
      #pragma unroll
      for (int fm = 0; fm < 4; ++fm) {
        int tl = wr*64 + fm*16 + (hi<<2);
        #pragma unroll
        for (int fn = 0; fn < 4; ++fn) {
          int h = wc*64 + fn*16 + l15;
          #pragma unroll
          for (int r = 0; r < 4; ++r) {
            float v = oacc[fm][fn][r] + Cbuf[(tl+r)*128 + h];
            ob[(size_t)(t0 + tl + r)*D_ + h] = f2bf(v);
          }
        }
      }
    }
    __syncthreads();   // Cbuf reads done -> K/V/Q regions reusable for next unit
  }
}

// ---------------- LN over D of attn_out, times u -> y (bf16)
__global__ __launch_bounds__(256) void ln_mul_kernel(
    const unsigned short* __restrict__ ain, const float* __restrict__ gamma,
    const float* __restrict__ beta, const unsigned short* __restrict__ u,
    unsigned short* __restrict__ y)
{
  int row = blockIdx.x, tid = threadIdx.x;
  ushort4 av = ((const ushort4*)(ain + (size_t)row*D_))[tid];
  float v0 = bf2f(av.x), v1 = bf2f(av.y), v2 = bf2f(av.z), v3 = bf2f(av.w);
  float s = v0+v1+v2+v3;
  float ss = v0*v0+v1*v1+v2*v2+v3*v3;
  #pragma unroll
  for (int o = 32; o; o >>= 1) { s += __shfl_down(s,o); ss += __shfl_down(ss,o); }
  __shared__ float red[8];
  int lane = tid&63, wid = tid>>6;
  if (lane==0) { red[wid]=s; red[4+wid]=ss; }
  __syncthreads();
  s = red[0]+red[1]+red[2]+red[3];
  ss = red[4]+red[5]+red[6]+red[7];
  float mean = s * (1.f/D_);
  float var  = ss * (1.f/D_) - mean*mean;
  float rstd = rsqrtf(var + EPS_);
  float4 g = ((const float4*)gamma)[tid], b = ((const float4*)beta)[tid];
  ushort4 uu = ((const ushort4*)(u + (size_t)row*D_))[tid];
  ushort4 o;
  o.x = f2bf(bf2f(uu.x) * ((v0-mean)*rstd*g.x + b.x));
  o.y = f2bf(bf2f(uu.y) * ((v1-mean)*rstd*g.y + b.y));
  o.z = f2bf(bf2f(uu.z) * ((v2-mean)*rstd*g.z + b.z));
  o.w = f2bf(bf2f(uu.w) * ((v3-mean)*rstd*g.w + b.w));
  ((ushort4*)(y + (size_t)row*D_))[tid] = o;
}

extern "C" void kernel_launch(void* const* d_in, const int* in_sizes, int n_in,
                              void* d_out, int out_size, void* d_ws, size_t ws_size,
                              hipStream_t stream) {
  const float* inputs = (const float*)d_in[0];
  // d_in[1] = attention_mask (guaranteed causal tril; not read)
  const float* g_in = (const float*)d_in[2];
  const float* b_in = (const float*)d_in[3];
  const float* wu = (const float*)d_in[4];
  const float* wq = (const float*)d_in[5];
  const float* wk = (const float*)d_in[6];
  const float* wv = (const float*)d_in[7];
  const float* g_at = (const float*)d_in[8];
  const float* b_at = (const float*)d_in[9];
  const float* wo = (const float*)d_in[10];
  float* out = (float*)d_out;

  char* ws = (char*)d_ws;
  unsigned short* x   = (unsigned short*)(ws + ((size_t)0));        // 16 MiB (reused as y)
  unsigned short* q   = (unsigned short*)(ws + ((size_t)16<<20));   // 16 MiB
  unsigned short* k   = (unsigned short*)(ws + ((size_t)32<<20));   // 16 MiB
  unsigned short* u   = (unsigned short*)(ws + ((size_t)48<<20));   // 16 MiB
  unsigned short* vt  = (unsigned short*)(ws + ((size_t)64<<20));   // 16 MiB
  unsigned short* wt  = (unsigned short*)(ws + ((size_t)80<<20));   // 10 MiB (5 x 2 MiB: u,q,k,v,o)
  unsigned short* ao  = (unsigned short*)(ws + ((size_t)96<<20));   // 16 MiB attn_out bf16
  unsigned short* y = x;

  wt_kernel<<<dim3(16,16,5), 256, 0, stream>>>(wu, wq, wk, wv, wo, wt);
  ln_in_kernel<<<BL_, 256, 0, stream>>>(inputs, g_in, b_in, x);
  gemm8p<0><<<dim3(32,16), 512, 0, stream>>>(x, wt, u, q, k, vt, nullptr, nullptr);
  attn_kernel<<<256, 512, 0, stream>>>(q, k, vt, ao);
  ln_mul_kernel<<<BL_, 256, 0, stream>>>(ao, g_at, b_at, u, y);
  gemm8p<1><<<dim3(32,8), 512, 0, stream>>>(y, wt + (size_t)4*D_*D_,
                                            nullptr, nullptr, nullptr, nullptr, inputs, out);
}

// Round 14
// 249.198 us; speedup vs baseline: 1.0756x; 1.0756x over previous
//
#include <hip/hip_runtime.h>
#include <hip/hip_bf16.h>
#include <stdint.h>

#define D_    1024
#define L_    2048
#define B_    4
#define NHEAD 8
#define HDIM  128
#define BL_   (B_*L_)   // 8192
#define EPS_  1e-6f

typedef __attribute__((ext_vector_type(8))) short short8;
typedef __attribute__((ext_vector_type(4))) float f32x4;

__device__ __forceinline__ unsigned short f2bf(float f) {
  unsigned u = __builtin_bit_cast(unsigned, f);
  unsigned r = 0x7fffu + ((u >> 16) & 1u);
  return (unsigned short)((u + r) >> 16);
}
__device__ __forceinline__ float bf2f(unsigned short h) {
  return __builtin_bit_cast(float, ((unsigned)h) << 16);
}
// fast silu: raw v_rcp (~1 ulp); output goes to bf16 so the error is invisible.
__device__ __forceinline__ float silu_f(float x) {
  return x * __builtin_amdgcn_rcpf(1.f + __expf(-x));
}
// pack two f32 -> two bf16 (RNE) in one instruction
__device__ __forceinline__ unsigned cvt_pk_bf16(float lo, float hi) {
  unsigned r;
  asm("v_cvt_pk_bf16_f32 %0, %1, %2" : "=v"(r) : "v"(lo), "v"(hi));
  return r;
}

// async global->LDS, 16B per lane; LDS dest is wave-uniform base + lane*16
__device__ __forceinline__ void gll16(const void* g, void* l) {
  auto gp = reinterpret_cast<const __attribute__((address_space(1))) unsigned*>(
      reinterpret_cast<uintptr_t>(g));
  auto lp = reinterpret_cast<__attribute__((address_space(3))) unsigned*>(
      (unsigned)reinterpret_cast<uintptr_t>(l));
  __builtin_amdgcn_global_load_lds(gp, lp, 16, 0, 0);
}

// ---------------- weight transpose + cast: w[1024][1024] f32 -> wt[1024][1024] bf16 (wt = w^T)
__global__ __launch_bounds__(256) void wt_kernel(
    const float* __restrict__ wu, const float* __restrict__ wq,
    const float* __restrict__ wk, const float* __restrict__ wv,
    const float* __restrict__ wo, unsigned short* __restrict__ wt)
{
  __shared__ float t[64][65];
  int mat = blockIdx.z;
  const float* src = mat==0?wu: mat==1?wq: mat==2?wk: mat==3?wv: wo;
  unsigned short* dst = wt + (size_t)mat*D_*D_;
  int r0 = blockIdx.y*64, c0 = blockIdx.x*64;
  int tid = threadIdx.x;
  for (int i = 0; i < 16; ++i) {
    int e = i*256 + tid; int r = e>>6, c = e&63;
    t[r][c] = src[(size_t)(r0+r)*D_ + c0 + c];
  }
  __syncthreads();
  for (int i = 0; i < 16; ++i) {
    int e = i*256 + tid; int r = e>>6, c = e&63;
    dst[(size_t)(c0+r)*D_ + r0 + c] = f2bf(t[c][r]);
  }
}

// ---------------- input LN -> bf16 x
__global__ __launch_bounds__(256) void ln_in_kernel(
    const float* __restrict__ in, const float* __restrict__ gamma,
    const float* __restrict__ beta, unsigned short* __restrict__ x)
{
  int row = blockIdx.x, tid = threadIdx.x;
  float4 v = ((const float4*)(in + (size_t)row*D_))[tid];
  float s = v.x+v.y+v.z+v.w;
  float ss = v.x*v.x + v.y*v.y + v.z*v.z + v.w*v.w;
  #pragma unroll
  for (int o = 32; o; o >>= 1) { s += __shfl_down(s,o); ss += __shfl_down(ss,o); }
  __shared__ float red[8];
  int lane = tid&63, wid = tid>>6;
  if (lane==0) { red[wid]=s; red[4+wid]=ss; }
  __syncthreads();
  s = red[0]+red[1]+red[2]+red[3];
  ss = red[4]+red[5]+red[6]+red[7];
  float mean = s * (1.f/D_);
  float var  = ss * (1.f/D_) - mean*mean;
  float rstd = rsqrtf(var + EPS_);
  float4 g = ((const float4*)gamma)[tid], b = ((const float4*)beta)[tid];
  ushort4 o;
  o.x = f2bf((v.x-mean)*rstd*g.x + b.x);
  o.y = f2bf((v.y-mean)*rstd*g.y + b.y);
  o.z = f2bf((v.z-mean)*rstd*g.z + b.z);
  o.w = f2bf((v.w-mean)*rstd*g.w + b.w);
  ((ushort4*)(x + (size_t)row*D_))[tid] = o;
}

// ---------------- 256xBN 8-phase GEMM (m201-style port), C = A[M][1024] * Bt[cols][1024]^T
// BK=64, 2 full-tile dbufs (A: 2x16384 ushorts; B: 2xBDS). 8 waves 2M x 4N,
// per-wave C = 128 x (BN/4): MF=8, NF=BN/64. Per K-tile 4 sandwich phases
// (kk-half x m-half): {read 4 af (+NF bfr at kk change, kept in regs); stage one
// half-tile of t+1 into dbuf d^1; barrier; lgkmcnt(0)+sched_barrier; setprio(1);
// 4xNF MFMA quadrant; setprio(0); barrier}. Counted drain: ONE vmcnt(0) at the
// tile-end barrier only (stage split [A0][A1,B0][B1][none] -> last half has >=1
// phase of slack). Ring safety: tile t reads dbuf d, all staging writes d^1;
// each phase's lgkm0 precedes its closing barrier, so cross-tile gll16-vs-read
// is barrier-separated.  [layout: A addr (k8*256+row)*8, B (k8*BN+col)*8 -- both
// linear-compatible with gll16 and conflict-free on ds_read_b128]
template<int MODE>
__global__ __launch_bounds__(512) __attribute__((amdgpu_waves_per_eu(2,2))) void gemm8p(
    const unsigned short* __restrict__ A, const unsigned short* __restrict__ Bt,
    unsigned short* __restrict__ o_u, unsigned short* __restrict__ o_q,
    unsigned short* __restrict__ o_k, unsigned short* __restrict__ o_vt,
    const float* __restrict__ resid, float* __restrict__ o_f)
{
  constexpr int BN  = (MODE==0) ? 256 : 128;
  constexpr int NF  = BN/64;               // 4 or 2 n-frags per wave
  constexpr int BDS = BN*64;               // B dbuf ushorts (16384 / 8192)
  const int K = 1024;

  __shared__ unsigned short lds[32768 + 2*BDS];

  int lane = threadIdx.x & 63, wid = threadIdx.x >> 6;
  int wr = wid >> 2, wc = wid & 3;
  int hi = lane >> 4, l15 = lane & 15;
  int m0 = blockIdx.x * 256;
  int n0 = blockIdx.y * BN;
  const unsigned short* Ab = A + (size_t)m0*K;
  const unsigned short* Bb = Bt + (size_t)n0*K;

  f32x4 acc[8][NF] = {};
  short8 bfr_[NF];

  auto stageA = [&](int d, int t1, int h) {
    #pragma unroll
    for (int j = 0; j < 2; ++j) {
      int c = wid*2 + j, k8 = c>>1, rh = c&1;
      gll16(Ab + (size_t)(h*128 + rh*64 + lane)*K + t1*64 + k8*8,
            &lds[d*16384 + (k8*256 + h*128 + rh*64)*8]);
    }
  };
  auto stageB = [&](int d, int t1, int h) {
    if constexpr (MODE==0) {
      #pragma unroll
      for (int j = 0; j < 2; ++j) {
        int c = wid*2 + j, k8 = c>>1, ch = c&1;
        gll16(Bb + (size_t)(h*128 + ch*64 + lane)*K + t1*64 + k8*8,
              &lds[32768 + d*16384 + (k8*256 + h*128 + ch*64)*8]);
      }
    } else {
      gll16(Bb + (size_t)(h*64 + lane)*K + t1*64 + wid*8,
            &lds[32768 + d*8192 + (wid*128 + h*64)*8]);
    }
  };

#define AFR(m_, kk_) (*(const short8*)&lds[d*16384 + (((kk_)*4+hi)*256 + wr*128 + (m_)*16 + l15)*8])
#define BFRD(n_, kk_) (*(const short8*)&lds[32768 + d*BDS + (((kk_)*4+hi)*BN + wc*(BN/4) + (n_)*16 + l15)*8])

  // prologue: stage tile 0 fully into dbuf 0
  stageA(0,0,0); stageA(0,0,1); stageB(0,0,0); stageB(0,0,1);
  asm volatile("s_waitcnt vmcnt(0)" ::: "memory");
  __builtin_amdgcn_s_barrier();

  #pragma unroll 2
  for (int t = 0; t < 16; ++t) {
    const int d = t & 1;
    const bool st = (t < 15);
    // ---- phase 0: kk=0, mh=0; stage A-h0(t+1)
    {
      #pragma unroll
      for (int n = 0; n < NF; ++n) bfr_[n] = BFRD(n, 0);
      short8 af_[4];
      #pragma unroll
      for (int i = 0; i < 4; ++i) af_[i] = AFR(i, 0);
      if (st) stageA(d^1, t+1, 0);
      __builtin_amdgcn_s_barrier();
      asm volatile("s_waitcnt lgkmcnt(0)" ::: "memory");
      __builtin_amdgcn_sched_barrier(0);
      __builtin_amdgcn_s_setprio(1);
      #pragma unroll
      for (int i = 0; i < 4; ++i)
        #pragma unroll
        for (int n = 0; n < NF; ++n)
          acc[i][n] = __builtin_amdgcn_mfma_f32_16x16x32_bf16(af_[i], bfr_[n], acc[i][n], 0,0,0);
      __builtin_amdgcn_s_setprio(0);
      __builtin_amdgcn_sched_barrier(0);
      __builtin_amdgcn_s_barrier();
    }
    // ---- phase 1: kk=0, mh=1; stage A-h1(t+1) + B-h0(t+1)
    {
      short8 af_[4];
      #pragma unroll
      for (int i = 0; i < 4; ++i) af_[i] = AFR(4+i, 0);
      if (st) { stageA(d^1, t+1, 1); stageB(d^1, t+1, 0); }
      __builtin_amdgcn_s_barrier();
      asm volatile("s_waitcnt lgkmcnt(0)" ::: "memory");
      __builtin_amdgcn_sched_barrier(0);
      __builtin_amdgcn_s_setprio(1);
      #pragma unroll
      for (int i = 0; i < 4; ++i)
        #pragma unroll
        for (int n = 0; n < NF; ++n)
          acc[4+i][n] = __builtin_amdgcn_mfma_f32_16x16x32_bf16(af_[i], bfr_[n], acc[4+i][n], 0,0,0);
      __builtin_amdgcn_s_setprio(0);
      __builtin_amdgcn_sched_barrier(0);
      __builtin_amdgcn_s_barrier();
    }
    // ---- phase 2: kk=1, mh=0; stage B-h1(t+1)
    {
      #pragma unroll
      for (int n = 0; n < NF; ++n) bfr_[n] = BFRD(n, 1);
      short8 af_[4];
      #pragma unroll
      for (int i = 0; i < 4; ++i) af_[i] = AFR(i, 1);
      if (st) stageB(d^1, t+1, 1);
      __builtin_amdgcn_s_barrier();
      asm volatile("s_waitcnt lgkmcnt(0)" ::: "memory");
      __builtin_amdgcn_sched_barrier(0);
      __builtin_amdgcn_s_setprio(1);
      #pragma unroll
      for (int i = 0; i < 4; ++i)
        #pragma unroll
        for (int n = 0; n < NF; ++n)
          acc[i][n] = __builtin_amdgcn_mfma_f32_16x16x32_bf16(af_[i], bfr_[n], acc[i][n], 0,0,0);
      __builtin_amdgcn_s_setprio(0);
      __builtin_amdgcn_sched_barrier(0);
      __builtin_amdgcn_s_barrier();
    }
    // ---- phase 3: kk=1, mh=1; no stage; tile-end counted drain vmcnt(0)
    {
      short8 af_[4];
      #pragma unroll
      for (int i = 0; i < 4; ++i) af_[i] = AFR(4+i, 1);
      __builtin_amdgcn_s_barrier();
      asm volatile("s_waitcnt lgkmcnt(0)" ::: "memory");
      __builtin_amdgcn_sched_barrier(0);
      __builtin_amdgcn_s_setprio(1);
      #pragma unroll
      for (int i = 0; i < 4; ++i)
        #pragma unroll
        for (int n = 0; n < NF; ++n)
          acc[4+i][n] = __builtin_amdgcn_mfma_f32_16x16x32_bf16(af_[i], bfr_[n], acc[4+i][n], 0,0,0);
      __builtin_amdgcn_s_setprio(0);
      asm volatile("s_waitcnt vmcnt(0)" ::: "memory");
      __builtin_amdgcn_sched_barrier(0);
      __builtin_amdgcn_s_barrier();
    }
  }
#undef AFR
#undef BFRD

  if constexpr (MODE == 0) {
    int mat = n0 >> 10;
    int jb = n0 & 1023;
    #pragma unroll
    for (int m = 0; m < 8; ++m) {
      int t_ = m0 + wr*128 + m*16 + (hi<<2);
      #pragma unroll
      for (int n = 0; n < NF; ++n) {
        int jj = jb + wc*64 + n*16 + l15;
        float p0 = silu_f(acc[m][n][0]);
        float p1 = silu_f(acc[m][n][1]);
        float p2 = silu_f(acc[m][n][2]);
        float p3 = silu_f(acc[m][n][3]);
        if (mat == 3) {
          int b = t_ >> 11, tt = t_ & 2047;
          int nn = jj >> 7, h = jj & 127;
          ushort4 pk;
          pk.x = f2bf(p0); pk.y = f2bf(p1); pk.z = f2bf(p2); pk.w = f2bf(p3);
          *(ushort4*)&o_vt[(((size_t)(b*NHEAD+nn))*HDIM + h)*L_ + tt] = pk;
        } else {
          unsigned short* dst = mat==0 ? o_u : (mat==1 ? o_q : o_k);
          dst[(size_t)(t_+0)*D_ + jj] = f2bf(p0);
          dst[(size_t)(t_+1)*D_ + jj] = f2bf(p1);
          dst[(size_t)(t_+2)*D_ + jj] = f2bf(p2);
          dst[(size_t)(t_+3)*D_ + jj] = f2bf(p3);
        }
      }
    }
  } else {
    #pragma unroll
    for (int m = 0; m < 8; ++m) {
      int t_ = m0 + wr*128 + m*16 + (hi<<2);
      #pragma unroll
      for (int n = 0; n < NF; ++n) {
        int jj = n0 + wc*32 + n*16 + l15;
        #pragma unroll
        for (int r = 0; r < 4; ++r)
          o_f[(size_t)(t_+r)*D_ + jj] = acc[m][n][r] + resid[(size_t)(t_+r)*D_ + jj];
      }
    }
  }
}

// ---------------- causal pointwise-silu attention, same-tile cooperative pairing
// (unchanged from R11: attn ~79us — see R11 notes)
__global__ __launch_bounds__(512) __attribute__((amdgpu_waves_per_eu(2,2))) void attn_kernel(
    const unsigned short* __restrict__ gq, const unsigned short* __restrict__ gk,
    const unsigned short* __restrict__ gvt, unsigned short* __restrict__ attn_out)
{
  __shared__ unsigned short SM[49152];   // 96 KB
  int id = blockIdx.x;
  int x = id & 7, c2 = (id >> 3) & 3, q = id >> 5;   // XCD, head-group, pair idx
  int bh = 8*c2 + x;
  int b = bh >> 3, n = bh & 7;
  const unsigned short* qb = gq + (size_t)b*L_*D_ + n*HDIM;
  const unsigned short* kb = gk + (size_t)b*L_*D_ + n*HDIM;
  const unsigned short* vb = gvt + (size_t)bh*HDIM*L_;
  unsigned short* ob = attn_out + (size_t)b*L_*D_ + n*HDIM;
  int lane = threadIdx.x & 63, wid = threadIdx.x >> 6;
  int wsel = wid >> 2, wq = wid & 3;      // set, wave-in-set
  int wr = wq >> 1, wc = wq & 1;
  int hi = lane >> 4, l15 = lane & 15;
  unsigned short* Kbuf = SM + (wsel ? 8192 : 0);
  unsigned short* Vbuf = SM + 16384 + (wsel ? 8192 : 0);
  unsigned short* Pbuf = SM + 32768 + (wsel ? 8192 : 0);
  unsigned short* Qbuf = SM + 32768;      // 32KB staging (PA+PB region)
  float* Cbuf = (float*)SM;               // 64KB combine (KA..VB region)

  for (int uu = 0; uu < 2; ++uu) {
    int ti = uu ? q : (15 - q);
    int t0 = ti * 128;
    // ---- stage Q tile [h/8(16)][t(128)][8] (all 8 waves, 32 chunks)
    #pragma unroll
    for (int i = 0; i < 4; ++i) {
      int cc = wid*4 + i;
      gll16(qb + (size_t)(t0 + ((cc&1)<<6) + lane)*D_ + ((cc>>1)<<3), &Qbuf[cc*512]);
    }
    __syncthreads();
    short8 qf[4][4];
    #pragma unroll
    for (int kk = 0; kk < 4; ++kk) {
      int kbase = (kk*4 + hi)*1024;
      #pragma unroll
      for (int fn = 0; fn < 4; ++fn)
        qf[kk][fn] = *(const short8*)&Qbuf[kbase + (wc*64 + fn*16 + l15)*8];
    }
    __syncthreads();   // qf in regs -> PA/PB free
    // ---- stage K/V chunk (wsel) for own set: K[h/8(16)][64][8], V[s/8(8)][128][8]
    #pragma unroll
    for (int i = 0; i < 4; ++i) {
      int cc = wq*4 + i;
      gll16(kb + (size_t)(wsel*64 + lane)*D_ + (cc<<3), &Kbuf[cc*512]);
      gll16(vb + (size_t)(((cc&1)<<6) + lane)*L_ + wsel*64 + ((cc>>1)<<3), &Vbuf[cc*512]);
    }
    __syncthreads();   // vmcnt(0): K0/V0 ready

    f32x4 oacc[4][4] = {};
    for (int j = 0; j <= ti; ++j) {
      bool stg = (j < ti);
      int cnext = 2*(j+1) + wsel;          // next 64-s chunk for this set
      // ===== R1: QK || K_next->regs || P-phase =====
      f32x4 sacc[2][4] = {};
      __builtin_amdgcn_s_setprio(1);
      #pragma unroll
      for (int kk = 0; kk < 4; ++kk) {
        int kbase = (kk*4 + hi)*512;
        short8 kf[2];
        #pragma unroll
        for (int fm = 0; fm < 2; ++fm)
          kf[fm] = *(const short8*)&Kbuf[kbase + (wr*32 + fm*16 + l15)*8];
        #pragma unroll
        for (int fm = 0; fm < 2; ++fm)
          #pragma unroll
          for (int fn = 0; fn < 4; ++fn)
            sacc[fm][fn] = __builtin_amdgcn_mfma_f32_16x16x32_bf16(kf[fm], qf[kk][fn], sacc[fm][fn], 0,0,0);
      }
      __builtin_amdgcn_s_setprio(0);
      uint4 kreg[4];
      if (stg) {
        #pragma unroll
        for (int i = 0; i < 4; ++i) {
          int cc = wq*4 + i;
          kreg[i] = *(const uint4*)(kb + (size_t)(cnext*64 + lane)*D_ + (cc<<3));
        }
      }
      // P = silu(S)/L with causal mask -> own P buffer [s/8(8)][t(128)][8]
      {
        bool diag = (j == ti);
        int maskoff = wsel*64;
        #pragma unroll
        for (int fm = 0; fm < 2; ++fm) {
          int sb = wr*32 + fm*16 + (hi<<2);
          #pragma unroll
          for (int fn = 0; fn < 4; ++fn) {
            int tl = wc*64 + fn*16 + l15;
            float pv[4];
            #pragma unroll
            for (int r = 0; r < 4; ++r) {
              float sv = silu_f(sacc[fm][fn][r]) * (1.f/2048.f);
              if (diag && (tl < maskoff + sb + r)) sv = 0.f;
              pv[r] = sv;
            }
            int a0 = (sb>>3)*1024 + tl*8 + (sb&7);
            *(unsigned*)&Pbuf[a0]   = cvt_pk_bf16(pv[0], pv[1]);
            *(unsigned*)&Pbuf[a0+2] = cvt_pk_bf16(pv[2], pv[3]);
          }
        }
      }
      // barrier A: P visible; K-regs + V(st) landed; QK ds_reads drained
      asm volatile("s_waitcnt vmcnt(0) lgkmcnt(0)" ::: "memory");
      __builtin_amdgcn_sched_barrier(0);
      __builtin_amdgcn_s_barrier();
      __builtin_amdgcn_sched_barrier(0);
      // ===== R2: K-commit || PV =====
      if (stg) {
        #pragma unroll
        for (int i = 0; i < 4; ++i) {
          int cc = wq*4 + i;
          *(uint4*)&Kbuf[cc*512 + lane*8] = kreg[i];
        }
      }
      __builtin_amdgcn_s_setprio(1);
      #pragma unroll
      for (int kk = 0; kk < 2; ++kk) {
        int kbase = (kk*4 + hi)*1024;
        short8 pa[4], vf[4];
        #pragma unroll
        for (int fm = 0; fm < 4; ++fm)
          pa[fm] = *(const short8*)&Pbuf[kbase + (wr*64 + fm*16 + l15)*8];
        #pragma unroll
        for (int fn = 0; fn < 4; ++fn)
          vf[fn] = *(const short8*)&Vbuf[kbase + (wc*64 + fn*16 + l15)*8];
        #pragma unroll
        for (int fm = 0; fm < 4; ++fm)
          #pragma unroll
          for (int fn = 0; fn < 4; ++fn)
            oacc[fm][fn] = __builtin_amdgcn_mfma_f32_16x16x32_bf16(pa[fm], vf[fn], oacc[fm][fn], 0,0,0);
      }
      __builtin_amdgcn_s_setprio(0);
      // barrier B: PV reads + K-commit writes drained
      asm volatile("s_waitcnt lgkmcnt(0)" ::: "memory");
      __builtin_amdgcn_sched_barrier(0);
      __builtin_amdgcn_s_barrier();
      __builtin_amdgcn_sched_barrier(0);
      // tail: issue V_next (lands under next R1; drained at next barrier A)
      if (stg) {
        #pragma unroll
        for (int i = 0; i < 4; ++i) {
          int cc = wq*4 + i;
          gll16(vb + (size_t)(((cc&1)<<6) + lane)*L_ + cnext*64 + ((cc>>1)<<3), &Vbuf[cc*512]);
        }
        __builtin_amdgcn_sched_barrier(0);
      }
    }
    // ---- combine partial O: set B writes f32 -> Cbuf, set A adds & stores
    if (wsel == 1) {
      #pragma unroll
      for (int fm = 0; fm < 4; ++fm) {
        int tl = wr*64 + fm*16 + (hi<<2);
        #pragma unroll
        for (int fn = 0; fn < 4; ++fn) {
          int h = wc*64 + fn*16 + l15;
          #pragma unroll
          for (int r = 0; r < 4; ++r)
            Cbuf[(tl+r)*128 + h] = oacc[fm][fn][r];
        }
      }
    }
    asm volatile("s_waitcnt lgkmcnt(0)" ::: "memory");
    __builtin_amdgcn_s_barrier();
    __builtin_amdgcn_sched_barrier(0);
    if (wsel == 0) {
      #pragma unroll
      for (int fm = 0; fm < 4; ++fm) {
        int tl = wr*64 + fm*16 + (hi<<2);
        #pragma unroll
        for (int fn = 0; fn < 4; ++fn) {
          int h = wc*64 + fn*16 + l15;
          #pragma unroll
          for (int r = 0; r < 4; ++r) {
            float v = oacc[fm][fn][r] + Cbuf[(tl+r)*128 + h];
            ob[(size_t)(t0 + tl + r)*D_ + h] = f2bf(v);
          }
        }
      }
    }
    __syncthreads();   // Cbuf reads done -> K/V/Q regions reusable for next unit
  }
}

// ---------------- LN over D of attn_out, times u -> y (bf16)
__global__ __launch_bounds__(256) void ln_mul_kernel(
    const unsigned short* __restrict__ ain, const float* __restrict__ gamma,
    const float* __restrict__ beta, const unsigned short* __restrict__ u,
    unsigned short* __restrict__ y)
{
  int row = blockIdx.x, tid = threadIdx.x;
  ushort4 av = ((const ushort4*)(ain + (size_t)row*D_))[tid];
  float v0 = bf2f(av.x), v1 = bf2f(av.y), v2 = bf2f(av.z), v3 = bf2f(av.w);
  float s = v0+v1+v2+v3;
  float ss = v0*v0+v1*v1+v2*v2+v3*v3;
  #pragma unroll
  for (int o = 32; o; o >>= 1) { s += __shfl_down(s,o); ss += __shfl_down(ss,o); }
  __shared__ float red[8];
  int lane = tid&63, wid = tid>>6;
  if (lane==0) { red[wid]=s; red[4+wid]=ss; }
  __syncthreads();
  s = red[0]+red[1]+red[2]+red[3];
  ss = red[4]+red[5]+red[6]+red[7];
  float mean = s * (1.f/D_);
  float var  = ss * (1.f/D_) - mean*mean;
  float rstd = rsqrtf(var + EPS_);
  float4 g = ((const float4*)gamma)[tid], b = ((const float4*)beta)[tid];
  ushort4 uu = ((const ushort4*)(u + (size_t)row*D_))[tid];
  ushort4 o;
  o.x = f2bf(bf2f(uu.x) * ((v0-mean)*rstd*g.x + b.x));
  o.y = f2bf(bf2f(uu.y) * ((v1-mean)*rstd*g.y + b.y));
  o.z = f2bf(bf2f(uu.z) * ((v2-mean)*rstd*g.z + b.z));
  o.w = f2bf(bf2f(uu.w) * ((v3-mean)*rstd*g.w + b.w));
  ((ushort4*)(y + (size_t)row*D_))[tid] = o;
}

extern "C" void kernel_launch(void* const* d_in, const int* in_sizes, int n_in,
                              void* d_out, int out_size, void* d_ws, size_t ws_size,
                              hipStream_t stream) {
  const float* inputs = (const float*)d_in[0];
  // d_in[1] = attention_mask (guaranteed causal tril; not read)
  const float* g_in = (const float*)d_in[2];
  const float* b_in = (const float*)d_in[3];
  const float* wu = (const float*)d_in[4];
  const float* wq = (const float*)d_in[5];
  const float* wk = (const float*)d_in[6];
  const float* wv = (const float*)d_in[7];
  const float* g_at = (const float*)d_in[8];
  const float* b_at = (const float*)d_in[9];
  const float* wo = (const float*)d_in[10];
  float* out = (float*)d_out;

  char* ws = (char*)d_ws;
  unsigned short* x   = (unsigned short*)(ws + ((size_t)0));        // 16 MiB (reused as y)
  unsigned short* q   = (unsigned short*)(ws + ((size_t)16<<20));   // 16 MiB
  unsigned short* k   = (unsigned short*)(ws + ((size_t)32<<20));   // 16 MiB
  unsigned short* u   = (unsigned short*)(ws + ((size_t)48<<20));   // 16 MiB
  unsigned short* vt  = (unsigned short*)(ws + ((size_t)64<<20));   // 16 MiB
  unsigned short* wt  = (unsigned short*)(ws + ((size_t)80<<20));   // 10 MiB (5 x 2 MiB: u,q,k,v,o)
  unsigned short* ao  = (unsigned short*)(ws + ((size_t)96<<20));   // 16 MiB attn_out bf16
  unsigned short* y = x;

  wt_kernel<<<dim3(16,16,5), 256, 0, stream>>>(wu, wq, wk, wv, wo, wt);
  ln_in_kernel<<<BL_, 256, 0, stream>>>(inputs, g_in, b_in, x);
  gemm8p<0><<<dim3(32,16), 512, 0, stream>>>(x, wt, u, q, k, vt, nullptr, nullptr);
  attn_kernel<<<256, 512, 0, stream>>>(q, k, vt, ao);
  ln_mul_kernel<<<BL_, 256, 0, stream>>>(ao, g_at, b_at, u, y);
  gemm8p<1><<<dim3(32,8), 512, 0, stream>>>(y, wt + (size_t)4*D_*D_,
                                            nullptr, nullptr, nullptr, nullptr, inputs, out);
}